// Round 1
// baseline (428.606 us; speedup 1.0000x reference)
//
#include <hip/hip_runtime.h>
#include <stdint.h>

#define BATCH 2
#define SEQ   4096
#define DM    2048
#define MT    (BATCH*SEQ)   /* 8192 rows total */
#define N1    (3*DM)        /* 6144 */
#define STRIP 16

typedef __attribute__((ext_vector_type(8))) __bf16 bf16x8;
typedef __attribute__((ext_vector_type(4))) float  f32x4;
typedef __attribute__((ext_vector_type(8))) unsigned short ushort8v;
typedef __attribute__((ext_vector_type(4))) unsigned short ushort4v;

__device__ inline unsigned short f2bf(float f) {
    uint32_t u = __float_as_uint(f);
    u += 0x7FFFu + ((u >> 16) & 1u);   // round-to-nearest-even
    return (unsigned short)(u >> 16);
}
__device__ inline float bf2f(unsigned short h) {
    return __uint_as_float(((uint32_t)h) << 16);
}

// ---------------- fp32 -> bf16 conversion (vectorized, grid-stride) --------
__global__ void cvt_f32_bf16(const float* __restrict__ src,
                             unsigned short* __restrict__ dst, int n) {
    int i = (blockIdx.x * blockDim.x + threadIdx.x) * 4;
    const int stride = gridDim.x * blockDim.x * 4;
    for (; i < n; i += stride) {
        const float4 v = *(const float4*)(src + i);
        ushort4v o;
        o[0] = f2bf(v.x); o[1] = f2bf(v.y); o[2] = f2bf(v.z); o[3] = f2bf(v.w);
        *(ushort4v*)(dst + i) = o;
    }
}

// ---------------- async global -> LDS (16B per lane) ------------------------
__device__ inline void async_copy16(const void* g, void* l) {
    __builtin_amdgcn_global_load_lds(
        (const __attribute__((address_space(1))) void*)g,
        (__attribute__((address_space(3))) void*)l,
        16, 0, 0);
}

// ---------------- bf16 MFMA GEMM: C[M][N] = A[M][K] * B[N][K]^T -------------
// m97 structure: 128x128 tile, BK=32, 4 waves (2x2), each wave 4x4 frags of
// 16x16x32. LDS linear (global_load_lds constraint), 2 barriers per K-step.
template <bool OUT_BF16>
__global__ __launch_bounds__(256)
void gemm_bt(const unsigned short* __restrict__ A,   // [M][K] bf16 bits
             const unsigned short* __restrict__ B,   // [N][K] bf16 bits
             void* __restrict__ Cout, int M, int N, int K) {
    __shared__ __attribute__((aligned(16))) unsigned short As[128 * 32];
    __shared__ __attribute__((aligned(16))) unsigned short Bs[128 * 32];
    const int tid  = threadIdx.x;
    const int wave = tid >> 6;
    const int lane = tid & 63;
    const int blockM = blockIdx.y * 128;
    const int blockN = blockIdx.x * 128;
    const int wm  = (wave >> 1) * 64;   // wave's M offset in tile
    const int wn  = (wave & 1) * 64;    // wave's N offset in tile
    const int l16 = lane & 15;
    const int lh  = lane >> 4;
    const int srow = lane >> 2;          // staging: row within 16-row chunk
    const int scol = (lane & 3) * 8;     // staging: k-offset (8 bf16 = 16B)

    const unsigned short* Abase = A + (size_t)blockM * K;
    const unsigned short* Bbase = B + (size_t)blockN * K;

    f32x4 acc[4][4] = {};

    for (int k0 = 0; k0 < K; k0 += 32) {
        // ---- stage 128x32 A-tile and B-tile via global_load_lds ----
        // chunk c covers LDS bytes [c*1024, c*1024+1024) = 16 rows of 32 bf16;
        // lane-linear LDS dest matches row-major [row][k] exactly.
        #pragma unroll
        for (int q = 0; q < 2; ++q) {
            const int c   = wave * 2 + q;            // 0..7
            const int row = c * 16 + srow;           // 0..127
            async_copy16(Abase + (size_t)row * K + k0 + scol, &As[c * 512]);
            async_copy16(Bbase + (size_t)row * K + k0 + scol, &Bs[c * 512]);
        }
        __syncthreads();   // compiler drains vmcnt(0) before s_barrier

        // ---- LDS -> fragments (ds_read_b128) ----
        bf16x8 af[4], bfr[4];
        #pragma unroll
        for (int i = 0; i < 4; ++i)
            af[i] = *(const bf16x8*)&As[(wm + i * 16 + l16) * 32 + lh * 8];
        #pragma unroll
        for (int j = 0; j < 4; ++j)
            bfr[j] = *(const bf16x8*)&Bs[(wn + j * 16 + l16) * 32 + lh * 8];

        // ---- 16 MFMA ----
        #pragma unroll
        for (int i = 0; i < 4; ++i)
            #pragma unroll
            for (int j = 0; j < 4; ++j)
                acc[i][j] = __builtin_amdgcn_mfma_f32_16x16x32_bf16(
                    af[i], bfr[j], acc[i][j], 0, 0, 0);
        __syncthreads();   // protect LDS before next stage overwrites
    }

    // ---- epilogue: C/D layout col=lane&15, row=(lane>>4)*4+reg (m89) ----
    #pragma unroll
    for (int i = 0; i < 4; ++i) {
        #pragma unroll
        for (int j = 0; j < 4; ++j) {
            #pragma unroll
            for (int r = 0; r < 4; ++r) {
                const int row = blockM + wm + i * 16 + lh * 4 + r;
                const int col = blockN + wn + j * 16 + l16;
                const float v = acc[i][j][r];
                if constexpr (OUT_BF16)
                    ((unsigned short*)Cout)[(size_t)row * N + col] = f2bf(v);
                else
                    ((float*)Cout)[(size_t)row * N + col] = v;
            }
        }
    }
}

// ---------------- fused u=Bg*Xg -> causal depthwise conv(K=3) -> Cg gate ----
// BCx: [MT][N1] bf16 bits, planes: Bg=[:,0:2048] Cg=[:,2048:4096] Xg=[:,4096:6144]
// gated[m][d] = Cg[m][d] * (w0*u[s-2] + w1*u[s-1] + w2*u[s]),  u zero for s<0.
__global__ void conv_gate_kernel(const unsigned short* __restrict__ BCx,
                                 const float* __restrict__ cw,   // [2048][3]
                                 unsigned short* __restrict__ gated) {
    const int tid = threadIdx.x;          // 256 threads: 8 channels each
    const int d0  = tid * 8;
    const int nstrips = SEQ / STRIP;      // 256
    const int b   = blockIdx.x / nstrips;
    const int s0  = (blockIdx.x % nstrips) * STRIP;

    float w0[8], w1c[8], w2c[8];
    #pragma unroll
    for (int c = 0; c < 8; ++c) {
        w0[c]  = cw[(d0 + c) * 3 + 0];
        w1c[c] = cw[(d0 + c) * 3 + 1];
        w2c[c] = cw[(d0 + c) * 3 + 2];
    }

    float um1[8], um2[8];
    if (s0 > 0) {
        const unsigned short* r2 = BCx + (size_t)(b * SEQ + s0 - 2) * N1;
        const unsigned short* r1 = BCx + (size_t)(b * SEQ + s0 - 1) * N1;
        ushort8v bg2 = *(const ushort8v*)(r2 + d0);
        ushort8v xg2 = *(const ushort8v*)(r2 + 2 * DM + d0);
        ushort8v bg1 = *(const ushort8v*)(r1 + d0);
        ushort8v xg1 = *(const ushort8v*)(r1 + 2 * DM + d0);
        #pragma unroll
        for (int c = 0; c < 8; ++c) {
            um2[c] = bf2f(bg2[c]) * bf2f(xg2[c]);
            um1[c] = bf2f(bg1[c]) * bf2f(xg1[c]);
        }
    } else {
        #pragma unroll
        for (int c = 0; c < 8; ++c) { um2[c] = 0.f; um1[c] = 0.f; }
    }

    for (int s = s0; s < s0 + STRIP; ++s) {
        const size_t m = (size_t)b * SEQ + s;
        const unsigned short* rp = BCx + m * N1;
        ushort8v bg = *(const ushort8v*)(rp + d0);
        ushort8v cg = *(const ushort8v*)(rp + DM + d0);
        ushort8v xg = *(const ushort8v*)(rp + 2 * DM + d0);
        ushort8v og;
        #pragma unroll
        for (int c = 0; c < 8; ++c) {
            const float u    = bf2f(bg[c]) * bf2f(xg[c]);
            const float conv = w0[c] * um2[c] + w1c[c] * um1[c] + w2c[c] * u;
            const float g    = bf2f(cg[c]) * conv;
            um2[c] = um1[c];
            um1[c] = u;
            og[c]  = f2bf(g);
        }
        *(ushort8v*)(gated + m * DM + d0) = og;
    }
}

// ---------------- launch ----------------------------------------------------
extern "C" void kernel_launch(void* const* d_in, const int* in_sizes, int n_in,
                              void* d_out, int out_size, void* d_ws, size_t ws_size,
                              hipStream_t stream) {
    const float* x   = (const float*)d_in[0];   // [2][4096][2048]
    const float* w1  = (const float*)d_in[1];   // [6144][2048]
    const float* w2  = (const float*)d_in[2];   // [2048][2048]
    const float* cw  = (const float*)d_in[3];   // [2048][1][3]
    float* out = (float*)d_out;                 // [2][4096][2048] fp32

    char* ws = (char*)d_ws;
    unsigned short* x_bf   = (unsigned short*)ws;                    // 33.5 MB
    unsigned short* w1_bf  = x_bf  + (size_t)MT * DM;                // 25.2 MB
    unsigned short* w2_bf  = w1_bf + (size_t)N1 * DM;                //  8.4 MB
    unsigned short* bcx_bf = w2_bf + (size_t)DM * DM;                // 100.7 MB
    unsigned short* g_bf   = bcx_bf + (size_t)MT * N1;               // 33.5 MB
    // total 192 MiB

    cvt_f32_bf16<<<2048, 256, 0, stream>>>(x,  x_bf,  MT * DM);
    cvt_f32_bf16<<<1024, 256, 0, stream>>>(w1, w1_bf, N1 * DM);
    cvt_f32_bf16<<<512,  256, 0, stream>>>(w2, w2_bf, DM * DM);

    // GEMM1: BCx[8192][6144] = x_bf[8192][2048] @ w1_bf[6144][2048]^T
    gemm_bt<true><<<dim3(N1 / 128, MT / 128), 256, 0, stream>>>(
        x_bf, w1_bf, bcx_bf, MT, N1, DM);

    // fused elementwise + causal depthwise conv + gate
    conv_gate_kernel<<<BATCH * (SEQ / STRIP), 256, 0, stream>>>(bcx_bf, cw, g_bf);

    // GEMM2: out[8192][2048] = g_bf[8192][2048] @ w2_bf[2048][2048]^T
    gemm_bt<false><<<dim3(DM / 128, MT / 128), 256, 0, stream>>>(
        g_bf, w2_bf, out, MT, DM, DM);
}

// Round 2
// 428.116 us; speedup vs baseline: 1.0011x; 1.0011x over previous
//
#include <hip/hip_runtime.h>
#include <stdint.h>

#define BATCH 2
#define SEQ   4096
#define DM    2048
#define MT    (BATCH*SEQ)   /* 8192 rows total */
#define N1    (3*DM)        /* 6144 */
#define STRIP 16

typedef __attribute__((ext_vector_type(8))) __bf16 bf16x8;
typedef __attribute__((ext_vector_type(4))) float  f32x4;
typedef __attribute__((ext_vector_type(8))) unsigned short ushort8v;
typedef __attribute__((ext_vector_type(4))) unsigned short ushort4v;

__device__ inline unsigned short f2bf(float f) {
    uint32_t u = __float_as_uint(f);
    u += 0x7FFFu + ((u >> 16) & 1u);   // round-to-nearest-even
    return (unsigned short)(u >> 16);
}
__device__ inline float bf2f(unsigned short h) {
    return __uint_as_float(((uint32_t)h) << 16);
}

// ---------------- fp32 -> bf16 conversion (vectorized, grid-stride) --------
__global__ void cvt_f32_bf16(const float* __restrict__ src,
                             unsigned short* __restrict__ dst, int n) {
    int i = (blockIdx.x * blockDim.x + threadIdx.x) * 4;
    const int stride = gridDim.x * blockDim.x * 4;
    for (; i < n; i += stride) {
        const float4 v = *(const float4*)(src + i);
        ushort4v o;
        o[0] = f2bf(v.x); o[1] = f2bf(v.y); o[2] = f2bf(v.z); o[3] = f2bf(v.w);
        *(ushort4v*)(dst + i) = o;
    }
}

// ---------------- async global -> LDS (16B per lane) ------------------------
__device__ inline void async_copy16(const void* g, void* l) {
    __builtin_amdgcn_global_load_lds(
        (const __attribute__((address_space(1))) void*)g,
        (__attribute__((address_space(3))) void*)l,
        16, 0, 0);
}

// ---------------- bf16 MFMA GEMM: C[M][N] = A[M][K] * B[N][K]^T -------------
// m97 structure: 128x128 tile, BK=32, 4 waves (2x2), each wave 4x4 frags of
// 16x16x32. LDS linear (global_load_lds constraint), 2 barriers per K-step.
template <bool OUT_BF16>
__global__ __launch_bounds__(256)
void gemm_bt(const unsigned short* __restrict__ A,   // [M][K] bf16 bits
             const unsigned short* __restrict__ B,   // [N][K] bf16 bits
             void* __restrict__ Cout, int M, int N, int K) {
    __shared__ __attribute__((aligned(16))) unsigned short As[128 * 32];
    __shared__ __attribute__((aligned(16))) unsigned short Bs[128 * 32];
    const int tid  = threadIdx.x;
    const int wave = tid >> 6;
    const int lane = tid & 63;
    const int blockM = blockIdx.y * 128;
    const int blockN = blockIdx.x * 128;
    const int wm  = (wave >> 1) * 64;   // wave's M offset in tile
    const int wn  = (wave & 1) * 64;    // wave's N offset in tile
    const int l16 = lane & 15;
    const int lh  = lane >> 4;
    const int srow = lane >> 2;          // staging: row within 16-row chunk
    const int scol = (lane & 3) * 8;     // staging: k-offset (8 bf16 = 16B)

    const unsigned short* Abase = A + (size_t)blockM * K;
    const unsigned short* Bbase = B + (size_t)blockN * K;

    f32x4 acc[4][4] = {};

    for (int k0 = 0; k0 < K; k0 += 32) {
        // ---- stage 128x32 A-tile and B-tile via global_load_lds ----
        // chunk c covers LDS bytes [c*1024, c*1024+1024) = 16 rows of 32 bf16;
        // lane-linear LDS dest matches row-major [row][k] exactly.
        #pragma unroll
        for (int q = 0; q < 2; ++q) {
            const int c   = wave * 2 + q;            // 0..7
            const int row = c * 16 + srow;           // 0..127
            async_copy16(Abase + (size_t)row * K + k0 + scol, &As[c * 512]);
            async_copy16(Bbase + (size_t)row * K + k0 + scol, &Bs[c * 512]);
        }
        __syncthreads();   // compiler drains vmcnt(0) before s_barrier

        // ---- LDS -> fragments (ds_read_b128) ----
        bf16x8 af[4], bfr[4];
        #pragma unroll
        for (int i = 0; i < 4; ++i)
            af[i] = *(const bf16x8*)&As[(wm + i * 16 + l16) * 32 + lh * 8];
        #pragma unroll
        for (int j = 0; j < 4; ++j)
            bfr[j] = *(const bf16x8*)&Bs[(wn + j * 16 + l16) * 32 + lh * 8];

        // ---- 16 MFMA ----
        #pragma unroll
        for (int i = 0; i < 4; ++i)
            #pragma unroll
            for (int j = 0; j < 4; ++j)
                acc[i][j] = __builtin_amdgcn_mfma_f32_16x16x32_bf16(
                    af[i], bfr[j], acc[i][j], 0, 0, 0);
        __syncthreads();   // protect LDS before next stage overwrites
    }

    // ---- epilogue: C/D layout col=lane&15, row=(lane>>4)*4+reg (m89) ----
    #pragma unroll
    for (int i = 0; i < 4; ++i) {
        #pragma unroll
        for (int j = 0; j < 4; ++j) {
            #pragma unroll
            for (int r = 0; r < 4; ++r) {
                const int row = blockM + wm + i * 16 + lh * 4 + r;
                const int col = blockN + wn + j * 16 + l16;
                const float v = acc[i][j][r];
                if constexpr (OUT_BF16)
                    ((unsigned short*)Cout)[(size_t)row * N + col] = f2bf(v);
                else
                    ((float*)Cout)[(size_t)row * N + col] = v;
            }
        }
    }
}

// ---------------- fused u=Bg*Xg -> causal depthwise conv(K=3) -> Cg gate ----
// BCx: [MT][N1] bf16 bits, planes: Bg=[:,0:2048] Cg=[:,2048:4096] Xg=[:,4096:6144]
// gated[m][d] = Cg[m][d] * (w0*u[s-2] + w1*u[s-1] + w2*u[s]),  u zero for s<0.
__global__ void conv_gate_kernel(const unsigned short* __restrict__ BCx,
                                 const float* __restrict__ cw,   // [2048][3]
                                 unsigned short* __restrict__ gated) {
    const int tid = threadIdx.x;          // 256 threads: 8 channels each
    const int d0  = tid * 8;
    const int nstrips = SEQ / STRIP;      // 256
    const int b   = blockIdx.x / nstrips;
    const int s0  = (blockIdx.x % nstrips) * STRIP;

    float w0[8], w1c[8], w2c[8];
    #pragma unroll
    for (int c = 0; c < 8; ++c) {
        w0[c]  = cw[(d0 + c) * 3 + 0];
        w1c[c] = cw[(d0 + c) * 3 + 1];
        w2c[c] = cw[(d0 + c) * 3 + 2];
    }

    float um1[8], um2[8];
    if (s0 > 0) {
        const unsigned short* r2 = BCx + (size_t)(b * SEQ + s0 - 2) * N1;
        const unsigned short* r1 = BCx + (size_t)(b * SEQ + s0 - 1) * N1;
        ushort8v bg2 = *(const ushort8v*)(r2 + d0);
        ushort8v xg2 = *(const ushort8v*)(r2 + 2 * DM + d0);
        ushort8v bg1 = *(const ushort8v*)(r1 + d0);
        ushort8v xg1 = *(const ushort8v*)(r1 + 2 * DM + d0);
        #pragma unroll
        for (int c = 0; c < 8; ++c) {
            um2[c] = bf2f(bg2[c]) * bf2f(xg2[c]);
            um1[c] = bf2f(bg1[c]) * bf2f(xg1[c]);
        }
    } else {
        #pragma unroll
        for (int c = 0; c < 8; ++c) { um2[c] = 0.f; um1[c] = 0.f; }
    }

    for (int s = s0; s < s0 + STRIP; ++s) {
        const size_t m = (size_t)b * SEQ + s;
        const unsigned short* rp = BCx + m * N1;
        ushort8v bg = *(const ushort8v*)(rp + d0);
        ushort8v cg = *(const ushort8v*)(rp + DM + d0);
        ushort8v xg = *(const ushort8v*)(rp + 2 * DM + d0);
        ushort8v og;
        #pragma unroll
        for (int c = 0; c < 8; ++c) {
            const float u    = bf2f(bg[c]) * bf2f(xg[c]);
            const float conv = w0[c] * um2[c] + w1c[c] * um1[c] + w2c[c] * u;
            const float g    = bf2f(cg[c]) * conv;
            um2[c] = um1[c];
            um1[c] = u;
            og[c]  = f2bf(g);
        }
        *(ushort8v*)(gated + m * DM + d0) = og;
    }
}

// ---------------- launch ----------------------------------------------------
extern "C" void kernel_launch(void* const* d_in, const int* in_sizes, int n_in,
                              void* d_out, int out_size, void* d_ws, size_t ws_size,
                              hipStream_t stream) {
    const float* x   = (const float*)d_in[0];   // [2][4096][2048]
    const float* w1  = (const float*)d_in[1];   // [6144][2048]
    const float* w2  = (const float*)d_in[2];   // [2048][2048]
    const float* cw  = (const float*)d_in[3];   // [2048][1][3]
    float* out = (float*)d_out;                 // [2][4096][2048] fp32

    char* ws = (char*)d_ws;
    unsigned short* x_bf   = (unsigned short*)ws;                    // 33.5 MB
    unsigned short* w1_bf  = x_bf  + (size_t)MT * DM;                // 25.2 MB
    unsigned short* w2_bf  = w1_bf + (size_t)N1 * DM;                //  8.4 MB
    unsigned short* bcx_bf = w2_bf + (size_t)DM * DM;                // 100.7 MB
    unsigned short* g_bf   = bcx_bf + (size_t)MT * N1;               // 33.5 MB
    // total 192 MiB

    cvt_f32_bf16<<<2048, 256, 0, stream>>>(x,  x_bf,  MT * DM);
    cvt_f32_bf16<<<1024, 256, 0, stream>>>(w1, w1_bf, N1 * DM);
    cvt_f32_bf16<<<512,  256, 0, stream>>>(w2, w2_bf, DM * DM);

    // GEMM1: BCx[8192][6144] = x_bf[8192][2048] @ w1_bf[6144][2048]^T
    gemm_bt<true><<<dim3(N1 / 128, MT / 128), 256, 0, stream>>>(
        x_bf, w1_bf, bcx_bf, MT, N1, DM);

    // fused elementwise + causal depthwise conv + gate
    conv_gate_kernel<<<BATCH * (SEQ / STRIP), 256, 0, stream>>>(bcx_bf, cw, g_bf);

    // GEMM2: out[8192][2048] = g_bf[8192][2048] @ w2_bf[2048][2048]^T
    gemm_bt<false><<<dim3(DM / 128, MT / 128), 256, 0, stream>>>(
        g_bf, w2_bf, out, MT, DM, DM);
}

// Round 3
// 311.659 us; speedup vs baseline: 1.3752x; 1.3737x over previous
//
#include <hip/hip_runtime.h>
#include <stdint.h>

#define BATCH 2
#define SEQ   4096
#define DM    2048
#define MT    (BATCH*SEQ)   /* 8192 rows total */
#define N1    (3*DM)        /* 6144 */
#define STRIP 16

typedef __attribute__((ext_vector_type(8))) __bf16 bf16x8;
typedef __attribute__((ext_vector_type(4))) float  f32x4;
typedef __attribute__((ext_vector_type(8))) unsigned short ushort8v;
typedef __attribute__((ext_vector_type(4))) unsigned short ushort4v;

__device__ inline unsigned short f2bf(float f) {
    uint32_t u = __float_as_uint(f);
    u += 0x7FFFu + ((u >> 16) & 1u);   // round-to-nearest-even
    return (unsigned short)(u >> 16);
}
__device__ inline float bf2f(unsigned short h) {
    return __uint_as_float(((uint32_t)h) << 16);
}

// ---------------- fp32 -> bf16 conversion (vectorized, grid-stride) --------
__global__ void cvt_f32_bf16(const float* __restrict__ src,
                             unsigned short* __restrict__ dst, int n) {
    int i = (blockIdx.x * blockDim.x + threadIdx.x) * 4;
    const int stride = gridDim.x * blockDim.x * 4;
    for (; i < n; i += stride) {
        const float4 v = *(const float4*)(src + i);
        ushort4v o;
        o[0] = f2bf(v.x); o[1] = f2bf(v.y); o[2] = f2bf(v.z); o[3] = f2bf(v.w);
        *(ushort4v*)(dst + i) = o;
    }
}

// ---------------- async global -> LDS (16B per lane) ------------------------
__device__ inline void async_copy16(const void* g, void* l) {
    __builtin_amdgcn_global_load_lds(
        (const __attribute__((address_space(1))) void*)g,
        (__attribute__((address_space(3))) void*)l,
        16, 0, 0);
}

// ===================== 256x256 8-phase bf16 GEMM (m201 template) ============
// C[M][N] = A[M][K] * B[N][K]^T.  BM=BN=256, BK=64, 512 threads (8 waves 2x4).
// LDS 128 KiB: 2 buffers x { A: 2 units x 128rows x 64, B: 2 nh-units }.
// Per phase: {ds_read frag subtile | stage 1 half-tile | barrier | lgkmcnt(0) |
// setprio(1) 16xMFMA setprio(0) | barrier}.  vmcnt(6) once per K-tile.
// XOR swizzle: lds byte col ^= (ldsrow&7)<<4, applied on BOTH stage-source and
// ds_read (involution).  B LDS unit nh holds n-rows with ((r>>5)&1)==nh.

#define MFMA_(d, a, b) d = __builtin_amdgcn_mfma_f32_16x16x32_bf16(a, b, d, 0, 0, 0)

#define QUAD(MH, NH, BQ) do { \
  MFMA_(acc[(MH)*4+0][(NH)*2+0], af[0][0], BQ[0][0]); MFMA_(acc[(MH)*4+0][(NH)*2+0], af[0][1], BQ[0][1]); \
  MFMA_(acc[(MH)*4+0][(NH)*2+1], af[0][0], BQ[1][0]); MFMA_(acc[(MH)*4+0][(NH)*2+1], af[0][1], BQ[1][1]); \
  MFMA_(acc[(MH)*4+1][(NH)*2+0], af[1][0], BQ[0][0]); MFMA_(acc[(MH)*4+1][(NH)*2+0], af[1][1], BQ[0][1]); \
  MFMA_(acc[(MH)*4+1][(NH)*2+1], af[1][0], BQ[1][0]); MFMA_(acc[(MH)*4+1][(NH)*2+1], af[1][1], BQ[1][1]); \
  MFMA_(acc[(MH)*4+2][(NH)*2+0], af[2][0], BQ[0][0]); MFMA_(acc[(MH)*4+2][(NH)*2+0], af[2][1], BQ[0][1]); \
  MFMA_(acc[(MH)*4+2][(NH)*2+1], af[2][0], BQ[1][0]); MFMA_(acc[(MH)*4+2][(NH)*2+1], af[2][1], BQ[1][1]); \
  MFMA_(acc[(MH)*4+3][(NH)*2+0], af[3][0], BQ[0][0]); MFMA_(acc[(MH)*4+3][(NH)*2+0], af[3][1], BQ[0][1]); \
  MFMA_(acc[(MH)*4+3][(NH)*2+1], af[3][0], BQ[1][0]); MFMA_(acc[(MH)*4+3][(NH)*2+1], af[3][1], BQ[1][1]); \
} while (0)

template <bool OUT_BF16>
__global__ __launch_bounds__(512)
void gemm256(const unsigned short* __restrict__ A,   // [M][K] bf16 bits
             const unsigned short* __restrict__ B,   // [N][K] bf16 bits
             void* __restrict__ Cout, int M, int N, int K) {
    __shared__ __attribute__((aligned(16))) char lds[131072];
    const int tid  = threadIdx.x;
    const int wave = tid >> 6;
    const int lane = tid & 63;
    const int wr = wave >> 2, wc = wave & 3;    // 2 x 4 wave grid
    const int l16 = lane & 15, lh = lane >> 4;
    const int NT = K >> 6;                      // K-tiles of 64

    // XCD-aware swizzle (grids here have nwg % 8 == 0 -> bijective)
    const int nx = gridDim.x;
    int flat = blockIdx.y * nx + blockIdx.x;
    const int cpx = (nx * gridDim.y) >> 3;
    flat = (flat & 7) * cpx + (flat >> 3);
    const int blockN = (flat % nx) << 8;
    const int blockM = (flat / nx) << 8;

    // ---- staging source addressing (pre-swizzled global col) ----
    // lds row within a load = wave*8 + (lane>>3); swizzle mask = (ldsrow&7)<<4
    const int swze = ((((lane & 7) << 4) ^ ((lane >> 3) << 4)) >> 1); // elems
    const int sr   = (wave << 3) + (lane >> 3);
    const unsigned short* Ab = A + (size_t)blockM * K;
    const unsigned short* Bb = B + (size_t)blockN * K;
    // A unit u, load d: global row = u*128 + d*64 + sr
    const size_t a00 = (size_t)(sr      ) * K + swze;
    const size_t a01 = (size_t)(sr +  64) * K + swze;
    const size_t a10 = (size_t)(sr + 128) * K + swze;
    const size_t a11 = (size_t)(sr + 192) * K + swze;
    // B unit nh, load d: lds row rr = d*64+wave*8+(lane>>3);
    // global n-row = (rr>>5)*64 + nh*32 + (rr&31)
    const int bsr = ((wave >> 2) << 6) + ((wave & 3) << 3) + (lane >> 3);
    const size_t b00 = (size_t)(bsr      ) * K + swze;   // nh=0,d=0
    const size_t b01 = (size_t)(bsr + 128) * K + swze;   // nh=0,d=1
    const size_t b10 = (size_t)(bsr +  32) * K + swze;   // nh=1,d=0
    const size_t b11 = (size_t)(bsr + 160) * K + swze;   // nh=1,d=1
    const int ldsw = wave << 10;   // per-wave 1 KiB slice of each 8 KiB load

#define STG_A(BUF, U, K0) do { \
    async_copy16(Ab + a##U##0 + (K0), lds + (BUF) + (U)*16384 + ldsw); \
    async_copy16(Ab + a##U##1 + (K0), lds + (BUF) + (U)*16384 + 8192 + ldsw); } while (0)
#define STG_B(BUF, NH, K0) do { \
    async_copy16(Bb + b##NH##0 + (K0), lds + (BUF) + 32768 + (NH)*16384 + ldsw); \
    async_copy16(Bb + b##NH##1 + (K0), lds + (BUF) + 32768 + (NH)*16384 + 8192 + ldsw); } while (0)

    // ---- fragment read addressing (swizzled) ----
    const int rdswz = (l16 & 7) << 4;           // == (ldsrow&7)<<4 for all reads
    const int ac0 = ((lh << 4)      ) ^ rdswz;  // kk=0 col bytes
    const int ac1 = (64 + (lh << 4)) ^ rdswz;   // kk=1 col bytes
    const int aRB = wr * 16384 + l16 * 128;
    const int bRB = 32768 + (wc * 32 + l16) * 128;

#define LDA_(BUF, I, C) (*(const bf16x8*)(lds + (BUF) + aRB + (I)*2048 + (C)))
#define LDB_(BUF, J, C) (*(const bf16x8*)(lds + (BUF) + bRB + ((J)>>1)*16384 + ((J)&1)*2048 + (C)))

    f32x4 acc[8][4] = {};
    bf16x8 af[4][2], bq0[2][2], bq1[2][2];

    // ---- prologue: tile0 (4 units) + tile1 (3 units); drain tile0 ----
    STG_B(0, 0, 0); STG_B(0, 1, 0); STG_A(0, 0, 0); STG_A(0, 1, 0);
    if (NT > 1) {
        STG_B(65536, 0, 64); STG_B(65536, 1, 64); STG_A(65536, 0, 64);
        asm volatile("s_waitcnt vmcnt(6)" ::: "memory");
    } else {
        asm volatile("s_waitcnt vmcnt(0)" ::: "memory");
    }
    __builtin_amdgcn_s_barrier();

#define ITER(CUR, NXT, T) do { \
    /* phase 0: read A[mh0]+B[nh0](t); stage t+1 A-unit1 -> NXT */ \
    af[0][0]=LDA_(CUR,0,ac0); af[0][1]=LDA_(CUR,0,ac1); \
    af[1][0]=LDA_(CUR,1,ac0); af[1][1]=LDA_(CUR,1,ac1); \
    af[2][0]=LDA_(CUR,2,ac0); af[2][1]=LDA_(CUR,2,ac1); \
    af[3][0]=LDA_(CUR,3,ac0); af[3][1]=LDA_(CUR,3,ac1); \
    bq0[0][0]=LDB_(CUR,0,ac0); bq0[0][1]=LDB_(CUR,0,ac1); \
    bq0[1][0]=LDB_(CUR,1,ac0); bq0[1][1]=LDB_(CUR,1,ac1); \
    if ((T) + 1 < NT) STG_A(NXT, 1, ((T)+1)*64); \
    __builtin_amdgcn_s_barrier(); \
    asm volatile("s_waitcnt lgkmcnt(0)" ::: "memory"); \
    __builtin_amdgcn_s_setprio(1); \
    QUAD(0, 0, bq0); \
    __builtin_amdgcn_s_setprio(0); \
    __builtin_amdgcn_s_barrier(); \
    /* phase 1: read B[nh1](t); stage t+2 B-unit0 -> CUR (nh0 done ph0) */ \
    bq1[0][0]=LDB_(CUR,2,ac0); bq1[0][1]=LDB_(CUR,2,ac1); \
    bq1[1][0]=LDB_(CUR,3,ac0); bq1[1][1]=LDB_(CUR,3,ac1); \
    if ((T) + 2 < NT) STG_B(CUR, 0, ((T)+2)*64); \
    __builtin_amdgcn_s_barrier(); \
    asm volatile("s_waitcnt lgkmcnt(0)" ::: "memory"); \
    __builtin_amdgcn_s_setprio(1); \
    QUAD(0, 1, bq1); \
    __builtin_amdgcn_s_setprio(0); \
    __builtin_amdgcn_s_barrier(); \
    /* phase 2: read A[mh1](t); stage t+2 B-unit1 -> CUR (nh1 done ph1) */ \
    af[0][0]=LDA_(CUR,4,ac0); af[0][1]=LDA_(CUR,4,ac1); \
    af[1][0]=LDA_(CUR,5,ac0); af[1][1]=LDA_(CUR,5,ac1); \
    af[2][0]=LDA_(CUR,6,ac0); af[2][1]=LDA_(CUR,6,ac1); \
    af[3][0]=LDA_(CUR,7,ac0); af[3][1]=LDA_(CUR,7,ac1); \
    if ((T) + 2 < NT) STG_B(CUR, 1, ((T)+2)*64); \
    __builtin_amdgcn_s_barrier(); \
    asm volatile("s_waitcnt lgkmcnt(0)" ::: "memory"); \
    __builtin_amdgcn_s_setprio(1); \
    QUAD(1, 1, bq1); \
    __builtin_amdgcn_s_setprio(0); \
    __builtin_amdgcn_s_barrier(); \
    /* phase 3: no reads; stage t+2 A-unit0 -> CUR (A done ph2); vmcnt gate */ \
    if ((T) + 2 < NT) STG_A(CUR, 0, ((T)+2)*64); \
    __builtin_amdgcn_s_barrier(); \
    __builtin_amdgcn_s_setprio(1); \
    QUAD(1, 0, bq0); \
    __builtin_amdgcn_s_setprio(0); \
    if ((T) + 2 < NT)      { asm volatile("s_waitcnt vmcnt(6)" ::: "memory"); } \
    else if ((T) + 1 < NT) { asm volatile("s_waitcnt vmcnt(0)" ::: "memory"); } \
    __builtin_amdgcn_s_barrier(); \
} while (0)

    for (int t = 0; t < NT; t += 2) {   // NT is even (K=2048 -> 32)
        ITER(0, 65536, t);
        ITER(65536, 0, t + 1);
    }

    // ---- epilogue: C/D layout col=lane&15, row=(lane>>4)*4+reg ----
    const int orow = blockM + wr * 128 + (lh << 2);
    const int ocol = blockN + wc * 64 + l16;
    #pragma unroll
    for (int i = 0; i < 8; ++i) {
        #pragma unroll
        for (int j = 0; j < 4; ++j) {
            #pragma unroll
            for (int r = 0; r < 4; ++r) {
                const int row = orow + i * 16 + r;
                const int col = ocol + j * 16;
                if constexpr (OUT_BF16)
                    ((unsigned short*)Cout)[(size_t)row * N + col] = f2bf(acc[i][j][r]);
                else
                    ((float*)Cout)[(size_t)row * N + col] = acc[i][j][r];
            }
        }
    }
#undef ITER
#undef LDA_
#undef LDB_
#undef STG_A
#undef STG_B
}

// ---------------- fused u=Bg*Xg -> causal depthwise conv(K=3) -> Cg gate ----
__global__ void conv_gate_kernel(const unsigned short* __restrict__ BCx,
                                 const float* __restrict__ cw,   // [2048][3]
                                 unsigned short* __restrict__ gated) {
    const int tid = threadIdx.x;          // 256 threads: 8 channels each
    const int d0  = tid * 8;
    const int nstrips = SEQ / STRIP;      // 256
    const int b   = blockIdx.x / nstrips;
    const int s0  = (blockIdx.x % nstrips) * STRIP;

    float w0[8], w1c[8], w2c[8];
    #pragma unroll
    for (int c = 0; c < 8; ++c) {
        w0[c]  = cw[(d0 + c) * 3 + 0];
        w1c[c] = cw[(d0 + c) * 3 + 1];
        w2c[c] = cw[(d0 + c) * 3 + 2];
    }

    float um1[8], um2[8];
    if (s0 > 0) {
        const unsigned short* r2 = BCx + (size_t)(b * SEQ + s0 - 2) * N1;
        const unsigned short* r1 = BCx + (size_t)(b * SEQ + s0 - 1) * N1;
        ushort8v bg2 = *(const ushort8v*)(r2 + d0);
        ushort8v xg2 = *(const ushort8v*)(r2 + 2 * DM + d0);
        ushort8v bg1 = *(const ushort8v*)(r1 + d0);
        ushort8v xg1 = *(const ushort8v*)(r1 + 2 * DM + d0);
        #pragma unroll
        for (int c = 0; c < 8; ++c) {
            um2[c] = bf2f(bg2[c]) * bf2f(xg2[c]);
            um1[c] = bf2f(bg1[c]) * bf2f(xg1[c]);
        }
    } else {
        #pragma unroll
        for (int c = 0; c < 8; ++c) { um2[c] = 0.f; um1[c] = 0.f; }
    }

    for (int s = s0; s < s0 + STRIP; ++s) {
        const size_t m = (size_t)b * SEQ + s;
        const unsigned short* rp = BCx + m * N1;
        ushort8v bg = *(const ushort8v*)(rp + d0);
        ushort8v cg = *(const ushort8v*)(rp + DM + d0);
        ushort8v xg = *(const ushort8v*)(rp + 2 * DM + d0);
        ushort8v og;
        #pragma unroll
        for (int c = 0; c < 8; ++c) {
            const float u    = bf2f(bg[c]) * bf2f(xg[c]);
            const float conv = w0[c] * um2[c] + w1c[c] * um1[c] + w2c[c] * u;
            const float g    = bf2f(cg[c]) * conv;
            um2[c] = um1[c];
            um1[c] = u;
            og[c]  = f2bf(g);
        }
        *(ushort8v*)(gated + m * DM + d0) = og;
    }
}

// ---------------- launch ----------------------------------------------------
extern "C" void kernel_launch(void* const* d_in, const int* in_sizes, int n_in,
                              void* d_out, int out_size, void* d_ws, size_t ws_size,
                              hipStream_t stream) {
    const float* x   = (const float*)d_in[0];   // [2][4096][2048]
    const float* w1  = (const float*)d_in[1];   // [6144][2048]
    const float* w2  = (const float*)d_in[2];   // [2048][2048]
    const float* cw  = (const float*)d_in[3];   // [2048][1][3]
    float* out = (float*)d_out;                 // [2][4096][2048] fp32

    char* ws = (char*)d_ws;
    unsigned short* x_bf   = (unsigned short*)ws;
    unsigned short* w1_bf  = x_bf  + (size_t)MT * DM;
    unsigned short* w2_bf  = w1_bf + (size_t)N1 * DM;
    unsigned short* bcx_bf = w2_bf + (size_t)DM * DM;
    unsigned short* g_bf   = bcx_bf + (size_t)MT * N1;

    cvt_f32_bf16<<<2048, 256, 0, stream>>>(x,  x_bf,  MT * DM);
    cvt_f32_bf16<<<1024, 256, 0, stream>>>(w1, w1_bf, N1 * DM);
    cvt_f32_bf16<<<512,  256, 0, stream>>>(w2, w2_bf, DM * DM);

    // GEMM1: BCx[8192][6144] = x_bf @ w1_bf^T   (grid 24x32 = 768 wgs, %8==0)
    gemm256<true><<<dim3(N1 / 256, MT / 256), 512, 0, stream>>>(
        x_bf, w1_bf, bcx_bf, MT, N1, DM);

    // fused elementwise + causal depthwise conv + gate
    conv_gate_kernel<<<BATCH * (SEQ / STRIP), 256, 0, stream>>>(bcx_bf, cw, g_bf);

    // GEMM2: out[8192][2048] = g_bf @ w2_bf^T   (grid 8x32 = 256 wgs, %8==0)
    gemm256<false><<<dim3(DM / 256, MT / 256), 512, 0, stream>>>(
        g_bf, w2_bf, out, MT, DM, DM);
}